// Round 11
// baseline (200.744 us; speedup 1.0000x reference)
//
#include <hip/hip_runtime.h>
#include <cstdint>

// Fused Bayesian LSTM: B=4096, T=200, IN=79, H=10 (gates G=40)
// One wave per batch row. 8-timestep tiles, 1-deep double-buffered staging
// (vmcnt(0) at tile top), rec pipelined one tile behind gate production.
// Cell state tracked scaled: C = -2c (exact power-of-2 folding).
// ws float layout (from prep):
//  [0,48)      bias_hat f32, gates 0..39, zero-padded to 48
//  [48,448)    Whh_hat f32 natural: 48 + k*40 + c
//  [512,2816)  Bh: bf16(W) as ushort[48][96], c-major (c*96+k), zero-padded
//  [2816,5120) Bl: bf16(W - float(Bh)) same layout
#define Bsz 4096
#define Tlen 200
#define INs 79
#define Hs 10
#define Gs 40

typedef __attribute__((ext_vector_type(8))) short bf16x8;
typedef __attribute__((ext_vector_type(4))) float f32x4;

__device__ __forceinline__ unsigned short f2bf(float x) {   // RNE f32->bf16
    unsigned u = __float_as_uint(x);
    return (unsigned short)((u + 0x7FFF + ((u >> 16) & 1)) >> 16);
}

__global__ void prep_kernel(const float* __restrict__ wih_mu, const float* __restrict__ wih_rho, const float* __restrict__ wih_eps,
                            const float* __restrict__ whh_mu, const float* __restrict__ whh_rho, const float* __restrict__ whh_eps,
                            const float* __restrict__ b_mu,   const float* __restrict__ b_rho,   const float* __restrict__ b_eps,
                            float* __restrict__ w) {
    int idx = blockIdx.x * 256 + threadIdx.x;
    if (idx < 4608) {                       // Wih -> Bh/Bl bf16 split, [48][96] c-major
        int c = idx / 96, k = idx % 96;
        float val = 0.0f;
        if (c < Gs && k < INs) {
            int s = k * Gs + c;
            float r = wih_rho[s];
            float sp = (r > 20.0f) ? r : log1pf(expf(r));
            val = fmaf(sp, wih_eps[s], wih_mu[s]);
        }
        unsigned short h = f2bf(val);
        float back = __uint_as_float((unsigned)h << 16);
        unsigned short l = f2bf(val - back);
        ((unsigned short*)(w + 512))[idx]  = h;
        ((unsigned short*)(w + 2816))[idx] = l;
    } else if (idx < 5008) {                // Whh f32 natural
        int m = idx - 4608;
        float r = whh_rho[m];
        float sp = (r > 20.0f) ? r : log1pf(expf(r));
        w[48 + m] = fmaf(sp, whh_eps[m], whh_mu[m]);
    } else if (idx < 5056) {                // bias f32, padded to 48
        int m = idx - 5008;
        float val = 0.0f;
        if (m < Gs) {
            float r = b_rho[m];
            float sp = (r > 20.0f) ? r : log1pf(expf(r));
            val = fmaf(sp, b_eps[m], b_mu[m]);
        }
        w[m] = val;
    }
}

__global__ __launch_bounds__(64, 4) void fused_kernel(
    const float* __restrict__ x, const float* __restrict__ w,
    const float* __restrict__ lin_w, const float* __restrict__ lin_b,
    float* __restrict__ out) {
    // LDS floats: xbuf[2][640] (8 rows x 79 each, 16B-aligned) | gbuf[8*42]
    __shared__ __align__(16) float sm[1280 + 336];
    float* gbuf = sm + 1280;

    const int b = blockIdx.x;
    const int lane = threadIdx.x;
    const int jj = lane & 15;
    const int kg8 = (lane >> 4) * 8;

    const unsigned short* Bh = (const unsigned short*)(w + 512);
    const unsigned short* Bl = (const unsigned short*)(w + 2816);

    int pj = (lane & 3) * 10 + (lane >> 2); if (pj > 39) pj = 39;  // gate col; clamp lanes >39
    const int ty = lane & 3;
    const float sA = (ty == 2) ? -2.0f : -1.0f;   // folded into wcs/gv (exact pow2)
    const float sM = (ty == 2) ? -4.0f : 1.0f;    // g-lane act = -2*tanh  (C = -2c)
    const float sC = (ty == 2) ?  2.0f : 0.0f;
    float wcs[Hs];
#pragma unroll
    for (int k = 0; k < Hs; ++k) wcs[k] = w[48 + k * Gs + pj] * sA;
    float bias3[3];
#pragma unroll
    for (int n = 0; n < 3; ++n) bias3[n] = w[n * 16 + jj];

    float hs[Hs];
#pragma unroll
    for (int k = 0; k < Hs; ++k) hs[k] = 0.0f;
    float C = 0.0f;                               // C = -2c

    const long xbaseB = (long)b * (Tlen * INs) * 4;   // bytes, 16B-aligned
    auto* ldsc = (__attribute__((address_space(3))) char*)sm;

    // stage 8 rows (2528B = 158 x 16B slots) into buf 0/1, linear LDS dest
    auto stage = [&](int t0, int buf) {
        long srcB = xbaseB + (long)t0 * INs * 4;
#pragma unroll
        for (int kk = 0; kk < 2; ++kk)
            __builtin_amdgcn_global_load_lds(
                (const __attribute__((address_space(1))) void*)((const char*)x + srcB + (kk * 64 + lane) * 16),
                (__attribute__((address_space(3))) void*)(ldsc + buf * 2560 + (kk * 64 + lane) * 16), 16, 0, 0);
        if (lane < 30)
            __builtin_amdgcn_global_load_lds(
                (const __attribute__((address_space(1))) void*)((const char*)x + srcB + (128 + lane) * 16),
                (__attribute__((address_space(3))) void*)(ldsc + buf * 2560 + (128 + lane) * 16), 16, 0, 0);
    };

    // gates for tile in buf: A-reads (rows dup'd via jj&7), K-pad MASKED to
    // exact zeros (kills every 0xNaN path), conv, 27 MFMA, gbuf rows 0-7.
    auto produce = [&](int buf) {
        const float* xr = sm + buf * 640 + (jj & 7) * INs;
        float f0[8], f1[8], f2[8];
#pragma unroll
        for (int e = 0; e < 8; ++e) f0[e] = xr[kg8 + e];
#pragma unroll
        for (int e = 0; e < 8; ++e) f1[e] = xr[32 + kg8 + e];
#pragma unroll
        for (int e = 0; e < 8; ++e) {
            float raw = xr[64 + kg8 + e];
            f2[e] = (kg8 + e < 15) ? raw : 0.0f;  // k = 64+kg8+e < 79; else exact 0
        }
        union { unsigned u[4]; bf16x8 v; } Ah[3], Al[3];
        const float* fp[3] = {f0, f1, f2};
#pragma unroll
        for (int ks = 0; ks < 3; ++ks) {
#pragma unroll
            for (int p = 0; p < 4; ++p) {
                float a = fp[ks][2 * p], bb = fp[ks][2 * p + 1];
                unsigned ua = __float_as_uint(a), ub = __float_as_uint(bb);
                Ah[ks].u[p] = __builtin_amdgcn_perm(ub, ua, 0x07060302);  // {hi(b),hi(a)}
                float ra = a  - __uint_as_float(ua & 0xFFFF0000u);        // exact residual
                float rb = bb - __uint_as_float(ub & 0xFFFF0000u);
                unsigned pk;
                asm("v_cvt_pk_bf16_f32 %0, %1, %2" : "=v"(pk) : "v"(ra), "v"(rb));
                Al[ks].u[p] = pk;
            }
        }
        f32x4 acc[3];
#pragma unroll
        for (int n = 0; n < 3; ++n)
            acc[n] = (f32x4){bias3[n], bias3[n], bias3[n], bias3[n]};
#pragma unroll
        for (int ks = 0; ks < 3; ++ks) {
            const int k0 = ks * 32;
#pragma unroll
            for (int n = 0; n < 3; ++n) {
                int boff = (n * 16 + jj) * 96 + k0 + kg8;
                bf16x8 bh = *(const bf16x8*)(Bh + boff);
                bf16x8 bl = *(const bf16x8*)(Bl + boff);
                acc[n] = __builtin_amdgcn_mfma_f32_16x16x32_bf16(Ah[ks].v, bh, acc[n], 0, 0, 0);
                acc[n] = __builtin_amdgcn_mfma_f32_16x16x32_bf16(Ah[ks].v, bl, acc[n], 0, 0, 0);
                acc[n] = __builtin_amdgcn_mfma_f32_16x16x32_bf16(Al[ks].v, bh, acc[n], 0, 0, 0);
            }
        }
        if ((lane >> 4) < 2) {                    // D rows 0-7 = timesteps
#pragma unroll
            for (int n = 0; n < 3; ++n) {
                if (n == 2 && jj >= 8) continue;
#pragma unroll
                for (int r = 0; r < 4; ++r)
                    gbuf[((lane >> 4) * 4 + r) * 42 + n * 16 + jj] = acc[n][r];
            }
        }
    };

    float gvp[8];
    auto loadgv = [&]() {
#pragma unroll
        for (int tt = 0; tt < 8; ++tt) gvp[tt] = gbuf[tt * 42 + pj] * sA;  // sA-folded
    };

    // one recurrence step; GV is the sA-scaled gate pre-activation
    auto step = [&](float GV) {
        float a0 = GV;                            // tree-split dot (2 chains)
        float a1 = hs[1] * wcs[1];
        a0 = fmaf(hs[0], wcs[0], a0); a1 = fmaf(hs[3], wcs[3], a1);
        a0 = fmaf(hs[2], wcs[2], a0); a1 = fmaf(hs[5], wcs[5], a1);
        a0 = fmaf(hs[4], wcs[4], a0); a1 = fmaf(hs[7], wcs[7], a1);
        a0 = fmaf(hs[6], wcs[6], a0); a1 = fmaf(hs[9], wcs[9], a1);
        a0 = fmaf(hs[8], wcs[8], a0);
        float acs = a0 + a1;                      // sA*pre_act
        float e  = __expf(acs);                   // e^(sA*pre)
        float sg = __builtin_amdgcn_rcpf(1.0f + e);
        float act = fmaf(sg, sM, sC);             // sigma(i,f,o) / -2*tanh(g)
        int ai = __float_as_int(act);
        float a1d = __int_as_float(__builtin_amdgcn_mov_dpp(ai, 0xB1, 0xF, 0xF, true));
        float a2d = __int_as_float(__builtin_amdgcn_mov_dpp(ai, 0x4E, 0xF, 0xF, true));
        float a3d = __int_as_float(__builtin_amdgcn_mov_dpp(ai, 0x1B, 0xF, 0xF, true));
        C = fmaf(a1d, C, act * a2d);              // C = f*C + i*(-2g)   (ty==0 lanes)
        float e2 = __expf(C);                     // e^(-2c), no serial mul
        float th = fmaf(2.0f, __builtin_amdgcn_rcpf(1.0f + e2), -1.0f);  // tanh(c)
        float hn = a3d * th;                      // h = o * tanh(c)
#pragma unroll
        for (int k = 0; k < Hs; ++k)
            hs[k] = __int_as_float(__builtin_amdgcn_readlane(__float_as_int(hn), 4 * k));
    };

    // prologue: tile 0
    stage(0, 0);
    asm volatile("s_waitcnt vmcnt(0)" ::: "memory");    // tile 0 staged
    stage(8, 1);                                        // prefetch tile 1
    produce(0);
    loadgv();

    for (int i = 1; i <= 24; ++i) {
        asm volatile("s_waitcnt vmcnt(0)" ::: "memory");// tile i staged (issued last iter)
        if (i < 24) stage((i + 1) * 8, (i + 1) & 1);    // prefetch tile i+1
        produce(i & 1);                                 // gates(i): MFMA pipe
#pragma unroll
        for (int tt = 0; tt < 8; ++tt) step(gvp[tt]);   // rec tile i-1: VALU, interleaves
        loadgv();                                       // gates(i) -> regs
    }
#pragma unroll
    for (int tt = 0; tt < 8; ++tt) step(gvp[tt]);       // rec tile 24

    if (lane == 0) {
        float o = lin_b[0];
#pragma unroll
        for (int k = 0; k < Hs; ++k) o = fmaf(hs[k], lin_w[k], o);
        out[b] = o;
    }
}

extern "C" void kernel_launch(void* const* d_in, const int* in_sizes, int n_in,
                              void* d_out, int out_size, void* d_ws, size_t ws_size,
                              hipStream_t stream) {
    const float* x = (const float*)d_in[0];
    float* w   = (float*)d_ws;
    float* out = (float*)d_out;

    prep_kernel<<<20, 256, 0, stream>>>(
        (const float*)d_in[1], (const float*)d_in[2], (const float*)d_in[3],
        (const float*)d_in[4], (const float*)d_in[5], (const float*)d_in[6],
        (const float*)d_in[7], (const float*)d_in[8], (const float*)d_in[9], w);

    fused_kernel<<<Bsz, 64, 0, stream>>>(
        x, w, (const float*)d_in[10], (const float*)d_in[11], out);
}

// Round 12
// 108.935 us; speedup vs baseline: 1.8428x; 1.8428x over previous
//
#include <hip/hip_runtime.h>
#include <cstdint>
#include <cmath>

// Fused Bayesian LSTM: B=4096, T=200, IN=79, H=10 (gates G=40)
// Round-8 structure (proven 105.8us, no spill) + occupancy fix: 128-thr
// blocks with 2 independent batch rows (waves) per block -> 20 waves/CU
// (vs 16), since the 16-blocks/CU limit was the occupancy cap.
// Scale folding (all exact pow2 / one f32 mul by LOG2E):
//   prep folds sA=(-1|-2 per gate type) into Bh/Bl/bias -> gates = sA*pre.
//   kernel folds LOG2E at loadgv/wcs -> exp2f direct (no on-chain v_mul).
//   cell tracked as C = -2*log2e*c (linear recurrence -> exact).
// ws float layout (from prep):
//  [0,48)      bias_hat*sA f32, gates 0..39, zero-padded to 48
//  [48,448)    Whh_hat f32 natural: 48 + k*40 + c
//  [512,2816)  Bh: bf16(sA*W) as ushort[48][96], c-major (c*96+k), zero-pad
//  [2816,5120) Bl: bf16(sA*W - float(Bh)) same layout
#define Bsz 4096
#define Tlen 200
#define INs 79
#define Hs 10
#define Gs 40
#define LOG2E 1.4426950408889634f

typedef __attribute__((ext_vector_type(8))) short bf16x8;
typedef __attribute__((ext_vector_type(4))) float f32x4;

__device__ __forceinline__ unsigned short f2bf(float x) {   // RNE f32->bf16
    unsigned u = __float_as_uint(x);
    return (unsigned short)((u + 0x7FFF + ((u >> 16) & 1)) >> 16);
}

__global__ void prep_kernel(const float* __restrict__ wih_mu, const float* __restrict__ wih_rho, const float* __restrict__ wih_eps,
                            const float* __restrict__ whh_mu, const float* __restrict__ whh_rho, const float* __restrict__ whh_eps,
                            const float* __restrict__ b_mu,   const float* __restrict__ b_rho,   const float* __restrict__ b_eps,
                            float* __restrict__ w) {
    int idx = blockIdx.x * 256 + threadIdx.x;
    if (idx < 4608) {                       // sA*Wih -> Bh/Bl bf16 split, [48][96] c-major
        int c = idx / 96, k = idx % 96;
        float val = 0.0f;
        if (c < Gs && k < INs) {
            int s = k * Gs + c;
            float r = wih_rho[s];
            float sp = (r > 20.0f) ? r : log1pf(expf(r));
            val = fmaf(sp, wih_eps[s], wih_mu[s]);
            val *= (c >= 20 && c < 30) ? -2.0f : -1.0f;   // fold sA (exact)
        }
        unsigned short h = f2bf(val);
        float back = __uint_as_float((unsigned)h << 16);
        unsigned short l = f2bf(val - back);
        ((unsigned short*)(w + 512))[idx]  = h;
        ((unsigned short*)(w + 2816))[idx] = l;
    } else if (idx < 5008) {                // Whh f32 natural
        int m = idx - 4608;
        float r = whh_rho[m];
        float sp = (r > 20.0f) ? r : log1pf(expf(r));
        w[48 + m] = fmaf(sp, whh_eps[m], whh_mu[m]);
    } else if (idx < 5056) {                // sA*bias f32, padded to 48
        int m = idx - 5008;
        float val = 0.0f;
        if (m < Gs) {
            float r = b_rho[m];
            float sp = (r > 20.0f) ? r : log1pf(expf(r));
            val = fmaf(sp, b_eps[m], b_mu[m]);
            val *= (m >= 20 && m < 30) ? -2.0f : -1.0f;   // fold sA (exact)
        }
        w[m] = val;
    }
}

// 128-thread block = 2 waves = 2 independent batch rows (no __syncthreads).
// Per wave, per 16-timestep tile: vmcnt(0) -> A ds_reads -> lgkmcnt(0) ->
// async-stage next tile -> cheap bf16 split -> 27 MFMA -> gates via LDS
// bounce -> 16 recurrence steps (DPP quad combine + readlane h-broadcast).
__global__ __launch_bounds__(128, 4) void fused_kernel(
    const float* __restrict__ x, const float* __restrict__ w,
    const float* __restrict__ lin_w, const float* __restrict__ lin_b,
    float* __restrict__ out) {
    // per-wave region: xbuf[1264] | zpad[16] | gbuf[16*42] = 1952 floats
    __shared__ __align__(16) float sm[2 * 1952];
    const int wv = threadIdx.x >> 6;
    const int lane = threadIdx.x & 63;
    float* xbuf = sm + wv * 1952;
    float* gbuf = xbuf + 1280;

    const int b = blockIdx.x * 2 + wv;
    const int jj = lane & 15;
    const int kg8 = (lane >> 4) * 8;

    if (lane < 16) xbuf[1264 + lane] = 0.0f;          // zero pad (wave-private)

    const unsigned short* Bh = (const unsigned short*)(w + 512);
    const unsigned short* Bl = (const unsigned short*)(w + 2816);

    int pj = (lane & 3) * 10 + (lane >> 2); if (pj > 39) pj = 39;  // gate col; clamp lanes >39
    const int ty = lane & 3;
    const float sAL = ((ty == 2) ? -2.0f : -1.0f) * LOG2E;
    const float sM  = (ty == 2) ? (-4.0f * LOG2E) : 1.0f;   // g-lane act = -2*log2e*tanh
    const float sC  = (ty == 2) ? ( 2.0f * LOG2E) : 0.0f;
    float wcs[Hs];
#pragma unroll
    for (int k = 0; k < Hs; ++k) wcs[k] = w[48 + k * Gs + pj] * sAL;
    float bias3[3];
#pragma unroll
    for (int n = 0; n < 3; ++n) bias3[n] = w[n * 16 + jj];

    float hs[Hs];
#pragma unroll
    for (int k = 0; k < Hs; ++k) hs[k] = 0.0f;
    float C = 0.0f;                                   // C = -2*log2e*c

    const long xbaseB = (long)b * (Tlen * INs) * 4;   // bytes, 16B-aligned
    const long xendB  = (long)Bsz * Tlen * INs * 4 - 16;
    auto* ldsc = (__attribute__((address_space(3))) char*)xbuf;

    auto stage = [&](int t0) {   // 16 rows x 79 f32 = 316 x 16B slots, linear dest
        long srcB = xbaseB + (long)t0 * INs * 4;
#pragma unroll
        for (int kk = 0; kk < 4; ++kk) {
            long off = srcB + (long)(kk * 64 + lane) * 16;
            if (off > xendB) off = xendB;             // clamp at array end
            __builtin_amdgcn_global_load_lds(
                (const __attribute__((address_space(1))) void*)((const char*)x + off),
                (__attribute__((address_space(3))) void*)(ldsc + (kk * 64 + lane) * 16), 16, 0, 0);
        }
        if (lane < 60) {
            long off = srcB + (long)(256 + lane) * 16;
            if (off > xendB) off = xendB;
            __builtin_amdgcn_global_load_lds(
                (const __attribute__((address_space(1))) void*)((const char*)x + off),
                (__attribute__((address_space(3))) void*)(ldsc + (256 + lane) * 16), 16, 0, 0);
        }
    };

    stage(0);

    for (int tile = 0; tile < 13; ++tile) {
        const int t0 = tile * 16;
        asm volatile("s_waitcnt vmcnt(0)" ::: "memory");   // staged tile ready

        // ---- A-fragment reads (f32) from LDS; K-pad masked to exact 0 ----
        float f0[8], f1[8], f2[8];
#pragma unroll
        for (int e = 0; e < 8; ++e) f0[e] = xbuf[jj * INs + kg8 + e];
#pragma unroll
        for (int e = 0; e < 8; ++e) f1[e] = xbuf[jj * INs + 32 + kg8 + e];
#pragma unroll
        for (int e = 0; e < 8; ++e) {
            float raw = xbuf[jj * INs + 64 + kg8 + e];
            f2[e] = (kg8 + e < 15) ? raw : 0.0f;           // k = 64+kg8+e < 79
        }
        asm volatile("s_waitcnt lgkmcnt(0)" ::: "memory"); // A in regs -> xbuf reusable
        if (tile < 12) stage(t0 + 16);                     // async prefetch next tile

        // ---- cheap bf16 split: hi=trunc (perm-pack), lo=exact residual ----
        union { unsigned u[4]; bf16x8 v; } Ah[3], Al[3];
        const float* fp[3] = {f0, f1, f2};
#pragma unroll
        for (int ks = 0; ks < 3; ++ks) {
#pragma unroll
            for (int p = 0; p < 4; ++p) {
                float a = fp[ks][2 * p], bb = fp[ks][2 * p + 1];
                unsigned ua = __float_as_uint(a), ub = __float_as_uint(bb);
                Ah[ks].u[p] = __builtin_amdgcn_perm(ub, ua, 0x07060302);  // {hi(b),hi(a)}
                float ra = a  - __uint_as_float(ua & 0xFFFF0000u);        // exact
                float rb = bb - __uint_as_float(ub & 0xFFFF0000u);
                unsigned pk;
                asm("v_cvt_pk_bf16_f32 %0, %1, %2" : "=v"(pk) : "v"(ra), "v"(rb));
                Al[ks].u[p] = pk;
            }
        }

        // ---- 27 MFMA: 3 K-steps x 3 N-tiles x 3 terms ----
        f32x4 acc[3];
#pragma unroll
        for (int n = 0; n < 3; ++n)
            acc[n] = (f32x4){bias3[n], bias3[n], bias3[n], bias3[n]};
#pragma unroll
        for (int ks = 0; ks < 3; ++ks) {
            const int k0 = ks * 32;
#pragma unroll
            for (int n = 0; n < 3; ++n) {
                int boff = (n * 16 + jj) * 96 + k0 + kg8;
                bf16x8 bh = *(const bf16x8*)(Bh + boff);
                bf16x8 bl = *(const bf16x8*)(Bl + boff);
                acc[n] = __builtin_amdgcn_mfma_f32_16x16x32_bf16(Ah[ks].v, bh, acc[n], 0, 0, 0);
                acc[n] = __builtin_amdgcn_mfma_f32_16x16x32_bf16(Ah[ks].v, bl, acc[n], 0, 0, 0);
                acc[n] = __builtin_amdgcn_mfma_f32_16x16x32_bf16(Al[ks].v, bh, acc[n], 0, 0, 0);
            }
        }

        // ---- gates -> LDS tile [16][42] (D row=(lane>>4)*4+r = timestep) ----
#pragma unroll
        for (int n = 0; n < 3; ++n) {
            if (n == 2 && jj >= 8) continue;               // cols 40..47 padding
#pragma unroll
            for (int r = 0; r < 4; ++r)
                gbuf[((lane >> 4) * 4 + r) * 42 + n * 16 + jj] = acc[n][r];
        }
        // ---- this tile's gates for lane's gate column pj, LOG2E-folded ----
        float gv[16];
#pragma unroll
        for (int tt = 0; tt < 16; ++tt) gv[tt] = gbuf[tt * 42 + pj] * LOG2E;

        // ---- recurrence (gates already sA*log2e-scaled) ----
#pragma unroll
        for (int tt = 0; tt < 16; ++tt) {
            if (t0 + tt < Tlen) {
                float a0 = gv[tt];                         // tree-split dot
                float a1 = hs[1] * wcs[1];
                a0 = fmaf(hs[0], wcs[0], a0); a1 = fmaf(hs[3], wcs[3], a1);
                a0 = fmaf(hs[2], wcs[2], a0); a1 = fmaf(hs[5], wcs[5], a1);
                a0 = fmaf(hs[4], wcs[4], a0); a1 = fmaf(hs[7], wcs[7], a1);
                a0 = fmaf(hs[6], wcs[6], a0); a1 = fmaf(hs[9], wcs[9], a1);
                a0 = fmaf(hs[8], wcs[8], a0);
                float acs = a0 + a1;                       // log2e*sA*pre
                float e  = exp2f(acs);                     // e^(sA*pre), native v_exp
                float sg = __builtin_amdgcn_rcpf(1.0f + e);
                float act = fmaf(sg, sM, sC);              // sigma / -2*log2e*tanh
                int ai = __float_as_int(act);
                float a1d = __int_as_float(__builtin_amdgcn_mov_dpp(ai, 0xB1, 0xF, 0xF, true));
                float a2d = __int_as_float(__builtin_amdgcn_mov_dpp(ai, 0x4E, 0xF, 0xF, true));
                float a3d = __int_as_float(__builtin_amdgcn_mov_dpp(ai, 0x1B, 0xF, 0xF, true));
                C = fmaf(a1d, C, act * a2d);               // C = f*C + i*(-2L g)
                float e2 = exp2f(C);                       // e^(-2c)
                float th = fmaf(2.0f, __builtin_amdgcn_rcpf(1.0f + e2), -1.0f);  // tanh(c)
                float hn = a3d * th;                       // h = o * tanh(c)
#pragma unroll
                for (int k = 0; k < Hs; ++k)
                    hs[k] = __int_as_float(__builtin_amdgcn_readlane(__float_as_int(hn), 4 * k));
            }
        }
    }

    if (lane == 0) {
        float o = lin_b[0];
#pragma unroll
        for (int k = 0; k < Hs; ++k) o = fmaf(hs[k], lin_w[k], o);
        out[b] = o;
    }
}

extern "C" void kernel_launch(void* const* d_in, const int* in_sizes, int n_in,
                              void* d_out, int out_size, void* d_ws, size_t ws_size,
                              hipStream_t stream) {
    const float* x = (const float*)d_in[0];
    float* w   = (float*)d_ws;
    float* out = (float*)d_out;

    prep_kernel<<<20, 256, 0, stream>>>(
        (const float*)d_in[1], (const float*)d_in[2], (const float*)d_in[3],
        (const float*)d_in[4], (const float*)d_in[5], (const float*)d_in[6],
        (const float*)d_in[7], (const float*)d_in[8], (const float*)d_in[9], w);

    fused_kernel<<<Bsz / 2, 128, 0, stream>>>(
        x, w, (const float*)d_in[10], (const float*)d_in[11], out);
}